// Round 2
// baseline (390.404 us; speedup 1.0000x reference)
//
#include <hip/hip_runtime.h>
#include <cstdint>
#include <cstddef>

// ---------- bf16 helpers (bit-level) ----------
__device__ __forceinline__ float bf2f(uint16_t u) {
    union { uint32_t i; float f; } w; w.i = ((uint32_t)u) << 16; return w.f;
}
__device__ __forceinline__ uint16_t f2bf(float f) {
    union { float f; uint32_t i; } w; w.f = f;
    uint32_t x = w.i;
    uint32_t r = (x + 0x7FFFu + ((x >> 16) & 1u)) >> 16;   // RNE
    return (uint16_t)r;
}

typedef __bf16 bf16x8 __attribute__((ext_vector_type(8)));
typedef float  f32x4  __attribute__((ext_vector_type(4)));

// async global->LDS, 16B per lane; LDS dest is wave-uniform base + lane*16
__device__ __forceinline__ void load_lds16(const void* gptr, void* lptr) {
    __builtin_amdgcn_global_load_lds(
        (__attribute__((address_space(1))) void*)gptr,
        (__attribute__((address_space(3))) void*)lptr,
        16, 0, 0);
}

// ---------- generic GEMM: C[M,N] = act(A[M,K] @ BT[N,K]^T + bias) ----------
// A: fp32 (AFP32=1, staged via cvt+ds_write) or bf16 (global_load_lds path)
// C: fp32 (OUTFP32=1) or bf16
// grid.x = N/128, grid.y = M/128, grid.z = batch; 256 thr = 4 waves, 2x2 wave grid
template<int AFP32, int OUTFP32, int RELU>
__global__ __launch_bounds__(256, 3)
void gemm_bt(const void* __restrict__ Av, const uint16_t* __restrict__ BT,
             const float* __restrict__ bias, void* __restrict__ Cv,
             int K, int lda, int ldb, int ldc,
             long long sA, long long sB, long long sC)
{
    __shared__ uint16_t As[128 * 32];
    __shared__ uint16_t Bs[128 * 32];

    const int t    = threadIdx.x;
    const int lane = t & 63;
    const int w    = t >> 6;        // wave 0..3
    const int quad = lane >> 4;     // 0..3
    const int l15  = lane & 15;
    const int wr   = w >> 1;        // wave row 0..1
    const int wc   = w & 1;         // wave col 0..1
    const int gm0  = blockIdx.y * 128;
    const int gn0  = blockIdx.x * 128;

    BT += (long long)blockIdx.z * sB;

    f32x4 acc[4][4] = {};

    const int ch_r = lane >> 2;        // row within 16-row chunk
    const int ch_c = (lane & 3) * 8;   // bf16 col offset (8 elems = 16B)

    for (int k0 = 0; k0 < K; k0 += 32) {
        __syncthreads();   // previous iter's LDS reads complete

        // ---- stage B tile (always bf16, async 16B) ----
        {
            int row = w * 16 + ch_r;
            load_lds16(BT + (size_t)(gn0 + row) * ldb + k0 + ch_c, (void*)(Bs + w * 512));
            load_lds16(BT + (size_t)(gn0 + row + 64) * ldb + k0 + ch_c, (void*)(Bs + (w + 4) * 512));
        }
        // ---- stage A tile ----
        if (AFP32) {
            const float* A = (const float*)Av + (long long)blockIdx.z * sA;
            const int row = t >> 1, half = t & 1;
            const float* ap = A + (size_t)(gm0 + row) * lda + k0 + half * 16;
            float4 f0 = ((const float4*)ap)[0];
            float4 f1 = ((const float4*)ap)[1];
            float4 f2 = ((const float4*)ap)[2];
            float4 f3 = ((const float4*)ap)[3];
            uint32_t p[8];
            p[0] = (uint32_t)f2bf(f0.x) | ((uint32_t)f2bf(f0.y) << 16);
            p[1] = (uint32_t)f2bf(f0.z) | ((uint32_t)f2bf(f0.w) << 16);
            p[2] = (uint32_t)f2bf(f1.x) | ((uint32_t)f2bf(f1.y) << 16);
            p[3] = (uint32_t)f2bf(f1.z) | ((uint32_t)f2bf(f1.w) << 16);
            p[4] = (uint32_t)f2bf(f2.x) | ((uint32_t)f2bf(f2.y) << 16);
            p[5] = (uint32_t)f2bf(f2.z) | ((uint32_t)f2bf(f2.w) << 16);
            p[6] = (uint32_t)f2bf(f3.x) | ((uint32_t)f2bf(f3.y) << 16);
            p[7] = (uint32_t)f2bf(f3.z) | ((uint32_t)f2bf(f3.w) << 16);
            uint4* d = (uint4*)(As + row * 32 + half * 16);
            d[0] = make_uint4(p[0], p[1], p[2], p[3]);
            d[1] = make_uint4(p[4], p[5], p[6], p[7]);
        } else {
            const uint16_t* A = (const uint16_t*)Av + (long long)blockIdx.z * sA;
            int row = w * 16 + ch_r;
            load_lds16(A + (size_t)(gm0 + row) * lda + k0 + ch_c, (void*)(As + w * 512));
            load_lds16(A + (size_t)(gm0 + row + 64) * lda + k0 + ch_c, (void*)(As + (w + 4) * 512));
        }
        __syncthreads();   // staging visible

        bf16x8 af[4], bfr[4];
#pragma unroll
        for (int i = 0; i < 4; i++) {
            af[i]  = *(const bf16x8*)(As + (wr * 64 + i * 16 + l15) * 32 + quad * 8);
            bfr[i] = *(const bf16x8*)(Bs + (wc * 64 + i * 16 + l15) * 32 + quad * 8);
        }
#pragma unroll
        for (int mi = 0; mi < 4; mi++)
#pragma unroll
            for (int ni = 0; ni < 4; ni++)
                acc[mi][ni] = __builtin_amdgcn_mfma_f32_16x16x32_bf16(af[mi], bfr[ni], acc[mi][ni], 0, 0, 0);
    }

    // epilogue: C/D layout col=lane&15, row=quad*4+reg
#pragma unroll
    for (int ni = 0; ni < 4; ni++) {
        const int gcol = gn0 + wc * 64 + ni * 16 + l15;
        const float bv = bias ? bias[gcol] : 0.0f;
#pragma unroll
        for (int mi = 0; mi < 4; mi++) {
#pragma unroll
            for (int r = 0; r < 4; r++) {
                const int grow = gm0 + wr * 64 + mi * 16 + quad * 4 + r;
                float v = acc[mi][ni][r] + bv;
                if (RELU) v = fmaxf(v, 0.0f);
                if (OUTFP32) {
                    float* C = (float*)Cv + (long long)blockIdx.z * sC;
                    C[(size_t)grow * ldc + gcol] = v;
                } else {
                    uint16_t* C = (uint16_t*)Cv + (long long)blockIdx.z * sC;
                    C[(size_t)grow * ldc + gcol] = f2bf(v);
                }
            }
        }
    }
}

// ---------- transpose fp32 -> bf16: dst[n][k] = bf16(src[k][n]) ----------
__global__ __launch_bounds__(256)
void transpose_f32_to_bf16(const float* __restrict__ src, uint16_t* __restrict__ dst,
                           int src_ld, int dst_ld)
{
    __shared__ uint16_t tile[64 * 65];
    const int k0 = blockIdx.y * 64, n0 = blockIdx.x * 64;
    const int t = threadIdx.x;
#pragma unroll
    for (int i = 0; i < 16; i++) {
        int idx = i * 256 + t;
        int r = idx >> 6, c = idx & 63;
        tile[c * 65 + r] = f2bf(src[(size_t)(k0 + r) * src_ld + n0 + c]);
    }
    __syncthreads();
#pragma unroll
    for (int i = 0; i < 16; i++) {
        int idx = i * 256 + t;
        int n = idx >> 6, k = idx & 63;
        dst[(size_t)(n0 + n) * dst_ld + k0 + k] = tile[n * 65 + k];
    }
}

// ---------- transpose bf16 -> bf16 (batched) ----------
__global__ __launch_bounds__(256)
void transpose_bf16(const uint16_t* __restrict__ src, uint16_t* __restrict__ dst,
                    int src_ld, int dst_ld, long long sS, long long sD)
{
    __shared__ uint16_t tile[64 * 65];
    src += (long long)blockIdx.z * sS;
    dst += (long long)blockIdx.z * sD;
    const int k0 = blockIdx.y * 64, n0 = blockIdx.x * 64;
    const int t = threadIdx.x;
#pragma unroll
    for (int i = 0; i < 16; i++) {
        int idx = i * 256 + t;
        int r = idx >> 6, c = idx & 63;
        tile[c * 65 + r] = src[(size_t)(k0 + r) * src_ld + n0 + c];
    }
    __syncthreads();
#pragma unroll
    for (int i = 0; i < 16; i++) {
        int idx = i * 256 + t;
        int n = idx >> 6, k = idx & 63;
        dst[(size_t)(n0 + n) * dst_ld + k0 + k] = tile[n * 65 + k];
    }
}

// ---------- in-place masked softmax over rows of S [8192 x 2048] fp32 ----------
__global__ __launch_bounds__(256)
void softmax_rows_f32(float* __restrict__ S, const int* __restrict__ mask, int L)
{
    const int row = blockIdx.x;
    const int b = row >> 11;                 // L == 2048
    float* rp = S + (size_t)row * L;
    const int* mrow = mask + (size_t)b * L;  // mask[b,0,k]
    const int t = threadIdx.x;
    const int c0 = t * 8;

    float v[8];
    *(float4*)(v + 0) = *(const float4*)(rp + c0);
    *(float4*)(v + 4) = *(const float4*)(rp + c0 + 4);
    bool mk[8];
    float lmax = -1e30f;
#pragma unroll
    for (int j = 0; j < 8; j++) {
        mk[j] = (mrow[c0 + j] != 0);
        if (mk[j]) lmax = fmaxf(lmax, v[j]);
    }
#pragma unroll
    for (int off = 32; off > 0; off >>= 1)
        lmax = fmaxf(lmax, __shfl_xor(lmax, off, 64));

    __shared__ float redm[4];
    __shared__ float reds[4];
    const int w = t >> 6, lane = t & 63;
    if (lane == 0) redm[w] = lmax;
    __syncthreads();
    lmax = fmaxf(fmaxf(redm[0], redm[1]), fmaxf(redm[2], redm[3]));

    float e[8];
    float lsum = 0.f;
#pragma unroll
    for (int j = 0; j < 8; j++) {
        e[j] = mk[j] ? __expf(v[j] - lmax) : 0.0f;
        lsum += e[j];
    }
#pragma unroll
    for (int off = 32; off > 0; off >>= 1)
        lsum += __shfl_xor(lsum, off, 64);
    if (lane == 0) reds[w] = lsum;
    __syncthreads();
    lsum = reds[0] + reds[1] + reds[2] + reds[3];

    const float inv = 1.0f / lsum;
#pragma unroll
    for (int j = 0; j < 8; j++) v[j] = e[j] * inv;
    *(float4*)(rp + c0)     = *(const float4*)(v + 0);
    *(float4*)(rp + c0 + 4) = *(const float4*)(v + 4);
}

extern "C" void kernel_launch(void* const* d_in, const int* in_sizes, int n_in,
                              void* d_out, int out_size, void* d_ws, size_t ws_size,
                              hipStream_t stream)
{
    const float* x    = (const float*)d_in[0];  // [4,2048,1024] fp32
    const int*   mask = (const int*)d_in[1];    // [4,1,2048] int32
    const float* W1   = (const float*)d_in[2];  // [1024,1024]
    const float* b1   = (const float*)d_in[3];  // [1024]
    const float* W2   = (const float*)d_in[4];  // [1024,2048]
    const float* b2   = (const float*)d_in[5];  // [2048]
    const float* D2L  = (const float*)d_in[6];  // [1024,4096]

    const int Lr = 2048, D = 1024, M = 4 * Lr;  // M = 8192
    float* outp = (float*)d_out;                // [8192][1024] fp32
    float* attn = outp + (size_t)M * D;         // [8192][2048] fp32

    // ws layout (bf16 elems): W1T | W2T | D2LT | h(->vT) | kv   = 29M elems = 58 MB
    uint16_t* W1T  = (uint16_t*)d_ws;                   // 1024*1024
    uint16_t* W2T  = W1T + 1024 * 1024;                 // 2048*1024
    uint16_t* D2LT = W2T + 2048 * 1024;                 // 2048*1024
    uint16_t* hbuf = D2LT + 2048 * 1024;                // 8192*1024
    uint16_t* kv   = hbuf + (size_t)M * D;              // 8192*2048
    uint16_t* vT   = hbuf;  // reuse h region after GEMM2 (4*1024*2048 = 8M elems)

    dim3 blk(256);

    // weight cast+transpose -> bf16 [N][K]
    transpose_f32_to_bf16<<<dim3(16, 16), blk, 0, stream>>>(W1,  W1T,  1024, 1024);
    transpose_f32_to_bf16<<<dim3(32, 16), blk, 0, stream>>>(W2,  W2T,  2048, 1024);
    transpose_f32_to_bf16<<<dim3(32, 16), blk, 0, stream>>>(D2L, D2LT, 4096, 1024);

    // h = relu(x @ W1 + b1)   [8192,1024] K=1024, A fp32, out bf16
    gemm_bt<1, 0, 1><<<dim3(8, 64, 1), blk, 0, stream>>>(x, W1T, b1, hbuf,
        1024, 1024, 1024, 1024, 0, 0, 0);

    // kv = h @ W2 + b2        [8192,2048] K=1024, A bf16, out bf16
    gemm_bt<0, 0, 0><<<dim3(16, 64, 1), blk, 0, stream>>>(hbuf, W2T, b2, kv,
        1024, 1024, 1024, 2048, 0, 0, 0);

    // vT[b] = transpose(kv[b][:,1024:2048]) -> [4][1024][2048] bf16
    transpose_bf16<<<dim3(16, 32, 4), blk, 0, stream>>>(kv + 1024, vT,
        2048, 2048, (long long)2048 * 2048, (long long)1024 * 2048);

    // scores = k @ D_to_L[:, :2048] -> attn (fp32, in d_out), K=1024
    gemm_bt<0, 1, 0><<<dim3(16, 64, 1), blk, 0, stream>>>(kv, D2LT, nullptr, attn,
        1024, 2048, 1024, 2048, 0, 0, 0);

    // masked softmax in-place (fp32)
    softmax_rows_f32<<<dim3(8192), blk, 0, stream>>>(attn, mask, Lr);

    // output = attn @ v (batched over 4), A fp32, out fp32, K=2048
    gemm_bt<1, 1, 0><<<dim3(8, 16, 4), blk, 0, stream>>>(attn, vT, nullptr, outp,
        2048, 2048, 2048, 1024,
        (long long)2048 * 2048, (long long)1024 * 2048, (long long)2048 * 1024);
}

// Round 3
// 359.097 us; speedup vs baseline: 1.0872x; 1.0872x over previous
//
#include <hip/hip_runtime.h>
#include <cstdint>
#include <cstddef>

// ---------- bf16 helpers (bit-level) ----------
__device__ __forceinline__ float bf2f(uint16_t u) {
    union { uint32_t i; float f; } w; w.i = ((uint32_t)u) << 16; return w.f;
}
__device__ __forceinline__ uint16_t f2bf(float f) {
    union { float f; uint32_t i; } w; w.f = f;
    uint32_t x = w.i;
    uint32_t r = (x + 0x7FFFu + ((x >> 16) & 1u)) >> 16;   // RNE
    return (uint16_t)r;
}

typedef __bf16 bf16x8 __attribute__((ext_vector_type(8)));
typedef float  f32x4  __attribute__((ext_vector_type(4)));

// async global->LDS, 16B per lane; LDS dest is wave-uniform base + lane*16
__device__ __forceinline__ void load_lds16(const void* gptr, void* lptr) {
    __builtin_amdgcn_global_load_lds(
        (__attribute__((address_space(1))) void*)gptr,
        (__attribute__((address_space(3))) void*)lptr,
        16, 0, 0);
}

// ---------- generic GEMM: C[M,N] = act(A[M,K] @ BT[N,K]^T + bias) ----------
// A: fp32 (AFP32=1, cvt+ds_write staging) or bf16 (global_load_lds path)
// C: fp32 (OUTFP32=1) or bf16
// XCD-aware swizzle: linear block id g -> xcd = g&7 (round-robin dispatch);
// each XCD owns an M-slice (and a batch slice when gridDim.z>1) so its 4MB L2
// holds A-slice + B instead of the whole problem. Requires:
//   8 % gridDim.z == 0, gridDim.y % (8/gridDim.z) == 0, total blocks % 8 == 0.
template<int AFP32, int OUTFP32, int RELU>
__global__ __launch_bounds__(256, 3)
void gemm_bt(const void* __restrict__ Av, const uint16_t* __restrict__ BT,
             const float* __restrict__ bias, void* __restrict__ Cv,
             int K, int lda, int ldb, int ldc,
             long long sA, long long sB, long long sC)
{
    __shared__ uint16_t As[128 * 32];
    __shared__ uint16_t Bs[128 * 32];

    // ---- XCD swizzle ----
    const int nx = (int)gridDim.x, ny = (int)gridDim.y, nz = (int)gridDim.z;
    const int g   = (int)blockIdx.x + nx * ((int)blockIdx.y + ny * (int)blockIdx.z);
    const int xcd = g & 7;
    const int ii  = g >> 3;
    const int xz  = 8 / nz;          // XCDs per batch
    const int bz  = xcd / xz;
    const int sub = xcd % xz;
    const int ypc = ny / xz;         // y-blocks per XCD
    const int by  = sub * ypc + ii % ypc;
    const int bx  = ii / ypc;

    const int t    = threadIdx.x;
    const int lane = t & 63;
    const int w    = t >> 6;        // wave 0..3
    const int quad = lane >> 4;     // 0..3
    const int l15  = lane & 15;
    const int wr   = w >> 1;        // wave row 0..1
    const int wc   = w & 1;         // wave col 0..1
    const int gm0  = by * 128;
    const int gn0  = bx * 128;

    BT += (long long)bz * sB;

    f32x4 acc[4][4] = {};

    const int ch_r = lane >> 2;        // row within 16-row chunk
    const int ch_c = (lane & 3) * 8;   // bf16 col offset (8 elems = 16B)

    for (int k0 = 0; k0 < K; k0 += 32) {
        __syncthreads();   // previous iter's LDS reads complete

        // ---- stage B tile (always bf16, async 16B) ----
        {
            int row = w * 16 + ch_r;
            load_lds16(BT + (size_t)(gn0 + row) * ldb + k0 + ch_c, (void*)(Bs + w * 512));
            load_lds16(BT + (size_t)(gn0 + row + 64) * ldb + k0 + ch_c, (void*)(Bs + (w + 4) * 512));
        }
        // ---- stage A tile ----
        if (AFP32) {
            const float* A = (const float*)Av + (long long)bz * sA;
            const int row = t >> 1, half = t & 1;
            const float* ap = A + (size_t)(gm0 + row) * lda + k0 + half * 16;
            float4 f0 = ((const float4*)ap)[0];
            float4 f1 = ((const float4*)ap)[1];
            float4 f2 = ((const float4*)ap)[2];
            float4 f3 = ((const float4*)ap)[3];
            union { __bf16 h[16]; uint4 q[2]; } u;
            u.h[0]  = (__bf16)f0.x; u.h[1]  = (__bf16)f0.y;
            u.h[2]  = (__bf16)f0.z; u.h[3]  = (__bf16)f0.w;
            u.h[4]  = (__bf16)f1.x; u.h[5]  = (__bf16)f1.y;
            u.h[6]  = (__bf16)f1.z; u.h[7]  = (__bf16)f1.w;
            u.h[8]  = (__bf16)f2.x; u.h[9]  = (__bf16)f2.y;
            u.h[10] = (__bf16)f2.z; u.h[11] = (__bf16)f2.w;
            u.h[12] = (__bf16)f3.x; u.h[13] = (__bf16)f3.y;
            u.h[14] = (__bf16)f3.z; u.h[15] = (__bf16)f3.w;
            uint4* d = (uint4*)(As + row * 32 + half * 16);
            d[0] = u.q[0];
            d[1] = u.q[1];
        } else {
            const uint16_t* A = (const uint16_t*)Av + (long long)bz * sA;
            int row = w * 16 + ch_r;
            load_lds16(A + (size_t)(gm0 + row) * lda + k0 + ch_c, (void*)(As + w * 512));
            load_lds16(A + (size_t)(gm0 + row + 64) * lda + k0 + ch_c, (void*)(As + (w + 4) * 512));
        }
        __syncthreads();   // staging visible

        bf16x8 af[4], bfr[4];
#pragma unroll
        for (int i = 0; i < 4; i++) {
            af[i]  = *(const bf16x8*)(As + (wr * 64 + i * 16 + l15) * 32 + quad * 8);
            bfr[i] = *(const bf16x8*)(Bs + (wc * 64 + i * 16 + l15) * 32 + quad * 8);
        }
#pragma unroll
        for (int mi = 0; mi < 4; mi++)
#pragma unroll
            for (int ni = 0; ni < 4; ni++)
                acc[mi][ni] = __builtin_amdgcn_mfma_f32_16x16x32_bf16(af[mi], bfr[ni], acc[mi][ni], 0, 0, 0);
    }

    // epilogue: C/D layout col=lane&15, row=quad*4+reg
#pragma unroll
    for (int ni = 0; ni < 4; ni++) {
        const int gcol = gn0 + wc * 64 + ni * 16 + l15;
        const float bv = bias ? bias[gcol] : 0.0f;
#pragma unroll
        for (int mi = 0; mi < 4; mi++) {
#pragma unroll
            for (int r = 0; r < 4; r++) {
                const int grow = gm0 + wr * 64 + mi * 16 + quad * 4 + r;
                float v = acc[mi][ni][r] + bv;
                if (RELU) v = fmaxf(v, 0.0f);
                if (OUTFP32) {
                    float* C = (float*)Cv + (long long)bz * sC;
                    C[(size_t)grow * ldc + gcol] = v;
                } else {
                    uint16_t* C = (uint16_t*)Cv + (long long)bz * sC;
                    C[(size_t)grow * ldc + gcol] = f2bf(v);
                }
            }
        }
    }
}

// ---------- transpose fp32 -> bf16: dst[n][k] = bf16(src[k][n]) ----------
__global__ __launch_bounds__(256)
void transpose_f32_to_bf16(const float* __restrict__ src, uint16_t* __restrict__ dst,
                           int src_ld, int dst_ld)
{
    __shared__ uint16_t tile[64 * 65];
    const int k0 = blockIdx.y * 64, n0 = blockIdx.x * 64;
    const int t = threadIdx.x;
#pragma unroll
    for (int i = 0; i < 16; i++) {
        int idx = i * 256 + t;
        int r = idx >> 6, c = idx & 63;
        tile[c * 65 + r] = f2bf(src[(size_t)(k0 + r) * src_ld + n0 + c]);
    }
    __syncthreads();
#pragma unroll
    for (int i = 0; i < 16; i++) {
        int idx = i * 256 + t;
        int n = idx >> 6, k = idx & 63;
        dst[(size_t)(n0 + n) * dst_ld + k0 + k] = tile[n * 65 + k];
    }
}

// ---------- transpose bf16 -> bf16 (batched) ----------
__global__ __launch_bounds__(256)
void transpose_bf16(const uint16_t* __restrict__ src, uint16_t* __restrict__ dst,
                    int src_ld, int dst_ld, long long sS, long long sD)
{
    __shared__ uint16_t tile[64 * 65];
    src += (long long)blockIdx.z * sS;
    dst += (long long)blockIdx.z * sD;
    const int k0 = blockIdx.y * 64, n0 = blockIdx.x * 64;
    const int t = threadIdx.x;
#pragma unroll
    for (int i = 0; i < 16; i++) {
        int idx = i * 256 + t;
        int r = idx >> 6, c = idx & 63;
        tile[c * 65 + r] = src[(size_t)(k0 + r) * src_ld + n0 + c];
    }
    __syncthreads();
#pragma unroll
    for (int i = 0; i < 16; i++) {
        int idx = i * 256 + t;
        int n = idx >> 6, k = idx & 63;
        dst[(size_t)(n0 + n) * dst_ld + k0 + k] = tile[n * 65 + k];
    }
}

// ---------- in-place masked softmax, fp32; also emits bf16 copy ----------
__global__ __launch_bounds__(256)
void softmax_rows_f32(float* __restrict__ S, uint16_t* __restrict__ Sbf,
                      const int* __restrict__ mask, int L)
{
    const int row = blockIdx.x;
    const int b = row >> 11;                 // L == 2048
    float* rp = S + (size_t)row * L;
    uint16_t* bp = Sbf + (size_t)row * L;
    const int* mrow = mask + (size_t)b * L;  // mask[b,0,k]
    const int t = threadIdx.x;
    const int c0 = t * 8;

    float v[8];
    *(float4*)(v + 0) = *(const float4*)(rp + c0);
    *(float4*)(v + 4) = *(const float4*)(rp + c0 + 4);
    bool mk[8];
    float lmax = -1e30f;
#pragma unroll
    for (int j = 0; j < 8; j++) {
        mk[j] = (mrow[c0 + j] != 0);
        if (mk[j]) lmax = fmaxf(lmax, v[j]);
    }
#pragma unroll
    for (int off = 32; off > 0; off >>= 1)
        lmax = fmaxf(lmax, __shfl_xor(lmax, off, 64));

    __shared__ float redm[4];
    __shared__ float reds[4];
    const int w = t >> 6, lane = t & 63;
    if (lane == 0) redm[w] = lmax;
    __syncthreads();
    lmax = fmaxf(fmaxf(redm[0], redm[1]), fmaxf(redm[2], redm[3]));

    float e[8];
    float lsum = 0.f;
#pragma unroll
    for (int j = 0; j < 8; j++) {
        e[j] = mk[j] ? __expf(v[j] - lmax) : 0.0f;
        lsum += e[j];
    }
#pragma unroll
    for (int off = 32; off > 0; off >>= 1)
        lsum += __shfl_xor(lsum, off, 64);
    if (lane == 0) reds[w] = lsum;
    __syncthreads();
    lsum = reds[0] + reds[1] + reds[2] + reds[3];

    const float inv = 1.0f / lsum;
    uint16_t ub[8];
#pragma unroll
    for (int j = 0; j < 8; j++) {
        v[j] = e[j] * inv;
        ub[j] = f2bf(v[j]);
    }
    *(float4*)(rp + c0)     = *(const float4*)(v + 0);
    *(float4*)(rp + c0 + 4) = *(const float4*)(v + 4);
    *(uint4*)(bp + c0)      = *(const uint4*)ub;
}

extern "C" void kernel_launch(void* const* d_in, const int* in_sizes, int n_in,
                              void* d_out, int out_size, void* d_ws, size_t ws_size,
                              hipStream_t stream)
{
    const float* x    = (const float*)d_in[0];  // [4,2048,1024] fp32
    const int*   mask = (const int*)d_in[1];    // [4,1,2048] int32
    const float* W1   = (const float*)d_in[2];  // [1024,1024]
    const float* b1   = (const float*)d_in[3];  // [1024]
    const float* W2   = (const float*)d_in[4];  // [1024,2048]
    const float* b2   = (const float*)d_in[5];  // [2048]
    const float* D2L  = (const float*)d_in[6];  // [1024,4096]

    const int Lr = 2048, D = 1024, M = 4 * Lr;  // M = 8192
    float* outp = (float*)d_out;                // [8192][1024] fp32
    float* attn = outp + (size_t)M * D;         // [8192][2048] fp32

    // ws layout (bf16 elems): W1T | W2T | D2LT | h(->vT) | kv(->attn_bf16) = 58 MB
    uint16_t* W1T  = (uint16_t*)d_ws;                   // 1024*1024
    uint16_t* W2T  = W1T + 1024 * 1024;                 // 2048*1024
    uint16_t* D2LT = W2T + 2048 * 1024;                 // 2048*1024
    uint16_t* hbuf = D2LT + 2048 * 1024;                // 8192*1024
    uint16_t* kv   = hbuf + (size_t)M * D;              // 8192*2048
    uint16_t* vT   = hbuf;   // reuse h region after GEMM2 (4*1024*2048 elems)
    uint16_t* abf  = kv;     // reuse kv region after scores GEMM (8192*2048 elems)

    dim3 blk(256);

    // weight cast+transpose -> bf16 [N][K]
    transpose_f32_to_bf16<<<dim3(16, 16), blk, 0, stream>>>(W1,  W1T,  1024, 1024);
    transpose_f32_to_bf16<<<dim3(32, 16), blk, 0, stream>>>(W2,  W2T,  2048, 1024);
    transpose_f32_to_bf16<<<dim3(32, 16), blk, 0, stream>>>(D2L, D2LT, 4096, 1024);

    // h = relu(x @ W1 + b1)   [8192,1024] K=1024, A fp32, out bf16
    gemm_bt<1, 0, 1><<<dim3(8, 64, 1), blk, 0, stream>>>(x, W1T, b1, hbuf,
        1024, 1024, 1024, 1024, 0, 0, 0);

    // kv = h @ W2 + b2        [8192,2048] K=1024, A bf16, out bf16
    gemm_bt<0, 0, 0><<<dim3(16, 64, 1), blk, 0, stream>>>(hbuf, W2T, b2, kv,
        1024, 1024, 1024, 2048, 0, 0, 0);

    // vT[b] = transpose(kv[b][:,1024:2048]) -> [4][1024][2048] bf16
    transpose_bf16<<<dim3(16, 32, 4), blk, 0, stream>>>(kv + 1024, vT,
        2048, 2048, (long long)2048 * 2048, (long long)1024 * 2048);

    // scores = k @ D_to_L[:, :2048] -> attn (fp32, in d_out), K=1024
    gemm_bt<0, 1, 0><<<dim3(16, 64, 1), blk, 0, stream>>>(kv, D2LT, nullptr, attn,
        1024, 2048, 1024, 2048, 0, 0, 0);

    // masked softmax in-place (fp32) + bf16 copy into dead kv region
    softmax_rows_f32<<<dim3(8192), blk, 0, stream>>>(attn, abf, mask, Lr);

    // output = attn @ v (batched over 4), A bf16, out fp32, K=2048
    gemm_bt<0, 1, 0><<<dim3(8, 16, 4), blk, 0, stream>>>(abf, vT, nullptr, outp,
        2048, 2048, 2048, 1024,
        (long long)2048 * 2048, (long long)1024 * 2048, (long long)2048 * 1024);
}